// Round 11
// baseline (714.294 us; speedup 1.0000x reference)
//
#include <hip/hip_runtime.h>
#include <math.h>

#define D 128
#define CT 2                       // source col-tiles (of 16) per wave
#define SRCS_PER_WAVE (CT * 16)    // 32
#define WAVES 4                    // waves per block; block covers 128 sources
#define BIAS 16.0f                 // keeps biased approx distance > 0 (u32 key ordering)
#define REFK 10                    // exact-refine candidates per source
#define TILEB 8192                 // 32-row A-tile bytes
#define BUFB  8448                 // tile + 256B tsq slot

typedef __attribute__((ext_vector_type(8))) short short8;   // 8 bf16 = 4 VGPR
typedef __attribute__((ext_vector_type(4))) float f32x4;

// fp32 -> bf16 bits, round-to-nearest-even
static __device__ __forceinline__ unsigned short f2bf(float x) {
    unsigned u = __float_as_uint(x);
    unsigned r = u + 0x7FFFu + ((u >> 16) & 1u);
    return (unsigned short)(r >> 16);
}

// v_med3_u32: single-op per-level sorted insert primitive
static __device__ __forceinline__ unsigned med3u(unsigned a, unsigned b, unsigned c) {
    unsigned d;
    asm("v_med3_u32 %0, %1, %2, %3" : "=v"(d) : "v"(a), "v"(b), "v"(c));
    return d;
}

// exact sorted-ascending top-5 insert: 4 med3 + 1 min
static __device__ __forceinline__ void ins5(unsigned st[5], unsigned k) {
    st[4] = med3u(st[4], st[3], k);
    st[3] = med3u(st[3], st[2], k);
    st[2] = med3u(st[2], st[1], k);
    st[1] = med3u(st[1], st[0], k);
    st[0] = st[0] < k ? st[0] : k;
}

// exact sorted-ascending top-10 insert: 9 med3 + 1 min
static __device__ __forceinline__ void ins10(unsigned st[REFK], unsigned k) {
    #pragma unroll
    for (int s = REFK - 1; s >= 1; --s) st[s] = med3u(st[s], st[s - 1], k);
    st[0] = st[0] < k ? st[0] : k;
}

static __device__ __forceinline__ void gload_lds16(const void* g, void* l) {
    __builtin_amdgcn_global_load_lds(
        (const __attribute__((address_space(1))) unsigned*)g,
        (__attribute__((address_space(3))) unsigned*)l, 16, 0, 0);
}
static __device__ __forceinline__ void gload_lds4(const void* g, void* l) {
    __builtin_amdgcn_global_load_lds(
        (const __attribute__((address_space(1))) unsigned*)g,
        (__attribute__((address_space(3))) unsigned*)l, 4, 0, 0);
}

// Phase 0: tgt (fp32) -> tbf = bf16(-2*tgt), PRE-SWIZZLED within each 16-row tile
// (16B-unit u of row r stored at u ^ (r&15)); pad rows (M..Mpad) zeros.
// tsqb = |t|^2 + BIAS (INF pads) for the hot loop; tsqe = exact |t|^2 for refine.
__global__ void prep_kernel(const float* __restrict__ tgt, unsigned short* __restrict__ tbf,
                            float* __restrict__ tsqb, float* __restrict__ tsqe,
                            int M, int Mpad) {
    int row  = blockIdx.x;
    int lane = threadIdx.x;  // 64; handles elems 2*lane, 2*lane+1
    if (row >= Mpad) return;
    float2 v = make_float2(0.f, 0.f);
    if (row < M) v = *(const float2*)(tgt + (size_t)row * D + lane * 2);
    unsigned pack = (unsigned)f2bf(-2.f * v.x) | ((unsigned)f2bf(-2.f * v.y) << 16);
    size_t byte = (size_t)row * 256 + (size_t)(((lane >> 2) ^ (row & 15)) * 16 + (lane & 3) * 4);
    *(unsigned*)((char*)tbf + byte) = pack;
    float ss = v.x * v.x + v.y * v.y;
    #pragma unroll
    for (int off = 1; off < 64; off <<= 1) ss += __shfl_xor(ss, off);
    if (lane == 0) {
        tsqe[row] = ss;
        tsqb[row] = (row < M) ? (ss + BIAS) : __builtin_inff();
    }
}

// Scan: 32-row tiles, TRIPLE-buffered, counted-vmcnt protocol (no vmcnt(0) in loop):
//   per macro t:  STAGE(t+2 -> buf[(t+2)%3]);  COMPUTE(buf[t%3]);
//                 s_waitcnt vmcnt(3); s_barrier     // retires stage(t+1), keeps stage(t+2)
// Each block (blockIdx.y = half) sweeps half the targets (108 macros, %3==0 by padding).
// Output: top-5 packed keys (dist bits | 13-bit j) per (source,row-class,half).
__global__ __launch_bounds__(256, 6)
void knn_scan(const float* __restrict__ src, const unsigned short* __restrict__ tbf,
              const float* __restrict__ tsqb, unsigned* __restrict__ keys,
              int N, int M, int h0, int msteps) {
    const int tid  = (int)threadIdx.x;
    const int wid  = tid >> 6;
    const int lane = tid & 63;
    const int c16  = lane & 15;   // MFMA col (source slot) / A-row within tile
    const int g    = lane >> 4;   // row-class (C rows 4g..4g+3)
    const int half = blockIdx.y;
    const int colbase = blockIdx.x * (WAVES * SRCS_PER_WAVE) + wid * SRCS_PER_WAVE;

    __shared__ __align__(16) char smem[3 * BUFB];   // 25344 B -> 6 blocks/CU

    // ---- build source (B) fragments: bf16, k = kk*32 + g*8 + e (matches A packing)
    short8 bfrag[CT][4];
    #pragma unroll
    for (int ct = 0; ct < CT; ++ct) {
        int srow = colbase + ct * 16 + c16;
        if (srow >= N) srow = N - 1;
        const float* sp = src + (size_t)srow * D + g * 8;
        #pragma unroll
        for (int kk = 0; kk < 4; ++kk) {
            float4 v0 = *(const float4*)(sp + kk * 32);
            float4 v1 = *(const float4*)(sp + kk * 32 + 4);
            short8 b;
            b[0] = (short)f2bf(v0.x); b[1] = (short)f2bf(v0.y);
            b[2] = (short)f2bf(v0.z); b[3] = (short)f2bf(v0.w);
            b[4] = (short)f2bf(v1.x); b[5] = (short)f2bf(v1.y);
            b[6] = (short)f2bf(v1.z); b[7] = (short)f2bf(v1.w);
            bfrag[ct][kk] = b;
        }
    }

    unsigned st[CT][5];
    #pragma unroll
    for (int ct = 0; ct < CT; ++ct)
        #pragma unroll
        for (int s = 0; s < 5; ++s) st[ct][s] = 0xFFFFFFFFu;

    // swizzled LDS element offsets (constant per thread)
    int oe[4];
    #pragma unroll
    for (int kk = 0; kk < 4; ++kk) oe[kk] = c16 * 16 + ((g + 4 * kk) ^ c16);

    const int t0 = half ? h0 : 0;
    const int tc = half ? (msteps - h0) : h0;   // 32-row macros in this half (%3==0)
    const int tlast = t0 + tc - 1;

    #define STAGE(tile, b)                                                          \
        do {                                                                        \
            const char* gb_ = (const char*)tbf + (size_t)(tile) * TILEB;            \
            char* lb_ = smem + (size_t)(b) * BUFB;                                  \
            gload_lds16(gb_ + wid * 2048 + lane * 16, lb_ + wid * 2048);            \
            gload_lds16(gb_ + wid * 2048 + 1024 + lane * 16, lb_ + wid * 2048 + 1024);\
            gload_lds4((const char*)tsqb + (size_t)(tile) * 128 + lane * 4,         \
                       lb_ + TILEB);                                                \
        } while (0)

    #define COMPUTE(b)                                                              \
        do {                                                                        \
            const short8* A_ = (const short8*)(smem + (size_t)(b) * BUFB);          \
            const float*  Q_ = (const float*)(smem + (size_t)(b) * BUFB + TILEB);   \
            _Pragma("unroll")                                                       \
            for (int sub_ = 0; sub_ < 2; ++sub_) {                                  \
                short8 a_[4];                                                       \
                _Pragma("unroll")                                                   \
                for (int kk = 0; kk < 4; ++kk) a_[kk] = A_[sub_ * 256 + oe[kk]];    \
                float4 q_ = *(const float4*)(Q_ + sub_ * 16 + g * 4);               \
                _Pragma("unroll")                                                   \
                for (int ct = 0; ct < CT; ++ct) {                                   \
                    f32x4 acc = { q_.x, q_.y, q_.z, q_.w };                         \
                    _Pragma("unroll")                                               \
                    for (int kk = 0; kk < 4; ++kk)                                  \
                        acc = __builtin_amdgcn_mfma_f32_16x16x32_bf16(              \
                                  a_[kk], bfrag[ct][kk], acc, 0, 0, 0);             \
                    _Pragma("unroll")                                               \
                    for (int e = 0; e < 4; ++e) {                                   \
                        unsigned key = (__float_as_uint(acc[e]) & 0xFFFFE000u)      \
                                       | (jb + (unsigned)e);                        \
                        ins5(st[ct], key);                                          \
                    }                                                               \
                }                                                                   \
                jb += 16;                                                           \
            }                                                                       \
        } while (0)

    unsigned jb = (unsigned)(t0 * 32 + g * 4);

    STAGE(t0, 0);
    STAGE(t0 + 1, 1);
    asm volatile("s_waitcnt vmcnt(3)\n\ts_barrier" ::: "memory");   // tile t0 ready

    for (int i = 0; i < tc; i += 3) {
        int t_ = t0 + i;
        int s2 = t_ + 2 < tlast ? t_ + 2 : tlast;
        int s3 = t_ + 3 < tlast ? t_ + 3 : tlast;
        int s4 = t_ + 4 < tlast ? t_ + 4 : tlast;
        STAGE(s2, 2);
        COMPUTE(0);
        asm volatile("s_waitcnt vmcnt(3)\n\ts_barrier" ::: "memory");
        STAGE(s3, 0);
        COMPUTE(1);
        asm volatile("s_waitcnt vmcnt(3)\n\ts_barrier" ::: "memory");
        STAGE(s4, 1);
        COMPUTE(2);
        asm volatile("s_waitcnt vmcnt(3)\n\ts_barrier" ::: "memory");
    }
    asm volatile("s_waitcnt vmcnt(0)" ::: "memory");   // drain dangling clamped stages
    #undef STAGE
    #undef COMPUTE

    // ---- emit candidate keys ----
    #pragma unroll
    for (int ct = 0; ct < CT; ++ct) {
        int srow = colbase + ct * 16 + c16;
        if (srow < N) {
            #pragma unroll
            for (int s = 0; s < 5; ++s)
                keys[(size_t)srow * 40 + half * 20 + g * 5 + s] = st[ct][s];
        }
    }
}

// Merge: 1 thread per source. Top-10 (by truncated bf16 key) of the 40
// candidates, exact fp32 refine of those 10, top-3 + softmax + output.
__global__ __launch_bounds__(256, 4)
void knn_merge(const float* __restrict__ src, const float* __restrict__ tgt,
               const float* __restrict__ tsqe, const unsigned* __restrict__ keys,
               const float* __restrict__ tpts, float* __restrict__ out,
               int N, int M) {
    int i = blockIdx.x * 256 + (int)threadIdx.x;
    if (i >= N) return;

    unsigned best[REFK];
    #pragma unroll
    for (int s = 0; s < REFK; ++s) best[s] = 0xFFFFFFFFu;

    const uint4* kp = (const uint4*)(keys + (size_t)i * 40);
    #pragma unroll
    for (int q = 0; q < 10; ++q) {
        uint4 kv = kp[q];
        ins10(best, kv.x); ins10(best, kv.y); ins10(best, kv.z); ins10(best, kv.w);
    }

    int js[REFK]; float dt[REFK];
    #pragma unroll
    for (int s = 0; s < REFK; ++s) {
        int j = (int)(best[s] & 0x1FFFu);
        js[s] = (j < M) ? j : (M - 1);
        dt[s] = 0.f;
    }

    const float4* sp = (const float4*)(src + (size_t)i * D);
    for (int kc = 0; kc < D / 4; ++kc) {
        float4 sv = sp[kc];
        #pragma unroll
        for (int s = 0; s < REFK; ++s) {
            float4 tv = *(const float4*)(tgt + (size_t)js[s] * D + kc * 4);
            dt[s] = fmaf(sv.x, tv.x, fmaf(sv.y, tv.y, fmaf(sv.z, tv.z, fmaf(sv.w, tv.w, dt[s]))));
        }
    }

    float d0 = __builtin_inff(), d1 = d0, d2 = d0;
    int i0 = 0, i1 = 0, i2 = 0;
    #pragma unroll
    for (int s = 0; s < REFK; ++s) {
        float dd = fmaf(-2.f, dt[s], tsqe[js[s]]);
        int jj = js[s];
        if (dd < d2) {
            if (dd < d1) {
                d2 = d1; i2 = i1;
                if (dd < d0) { d1 = d0; i1 = i0; d0 = dd; i0 = jj; }
                else         { d1 = dd; i1 = jj; }
            } else { d2 = dd; i2 = jj; }
        }
    }

    float e1 = __expf(d0 - d1);
    float e2 = __expf(d0 - d2);
    float inv = 1.f / (1.f + e1 + e2);
    float w0 = inv, w1 = e1 * inv, w2 = e2 * inv;
    const float* p0 = tpts + 3 * (size_t)i0;
    const float* p1 = tpts + 3 * (size_t)i1;
    const float* p2 = tpts + 3 * (size_t)i2;
    out[3 * (size_t)i + 0] = w0 * p0[0] + w1 * p1[0] + w2 * p2[0];
    out[3 * (size_t)i + 1] = w0 * p0[1] + w1 * p1[1] + w2 * p2[1];
    out[3 * (size_t)i + 2] = w0 * p0[2] + w1 * p1[2] + w2 * p2[2];
}

extern "C" void kernel_launch(void* const* d_in, const int* in_sizes, int n_in,
                              void* d_out, int out_size, void* d_ws, size_t ws_size,
                              hipStream_t stream) {
    const float* src  = (const float*)d_in[0];  // [N,128]
    const float* tgt  = (const float*)d_in[1];  // [M,128]
    const float* tpts = (const float*)d_in[2];  // [M,3]
    float* out = (float*)d_out;

    int N = in_sizes[0] / D;
    int M = in_sizes[1] / D;
    int Mpad = (M + 191) & ~191;                // 192-multiple: 6912; msteps %6 == 0
    int msteps = Mpad >> 5;                     // 216 (32-row tiles)
    int h0 = msteps >> 1;                       // 108 (divisible by 3)

    // ws layout: tbf (Mpad*256 B, swizzled) | tsqb (Mpad*4) | tsqe (Mpad*4) |
    //            keys (N*40*4 = 16 MB). Total ~17.8 MB.
    char* w = (char*)d_ws;
    unsigned short* tbf = (unsigned short*)w;                 w += (size_t)Mpad * 256;
    float* tsqb = (float*)w;                                  w += (size_t)Mpad * 4;
    float* tsqe = (float*)w;                                  w += (size_t)Mpad * 4;
    unsigned* keys = (unsigned*)w;

    prep_kernel<<<Mpad, 64, 0, stream>>>(tgt, tbf, tsqb, tsqe, M, Mpad);

    int per_block = WAVES * SRCS_PER_WAVE;                    // 128
    dim3 sgrid((N + per_block - 1) / per_block, 2);           // 782 x 2 = 1564 blocks
    knn_scan<<<sgrid, 256, 0, stream>>>(src, tbf, tsqb, keys, N, M, h0, msteps);

    knn_merge<<<(N + 255) / 256, 256, 0, stream>>>(src, tgt, tsqe, keys, tpts, out, N, M);
}

// Round 12
// 417.111 us; speedup vs baseline: 1.7125x; 1.7125x over previous
//
#include <hip/hip_runtime.h>
#include <math.h>

#define D 128
#define CT 2                       // source col-tiles (of 16) per wave
#define SRCS_PER_WAVE (CT * 16)    // 32
#define WAVES 4                    // waves per block; block covers 128 sources
#define BIAS 16.0f                 // keeps biased approx distance > 0 (u32 key ordering)
#define REFK 10                    // exact-refine candidates per source
#define TILEB 8192                 // 32-row A-tile bytes
#define BUFB  8448                 // tile + 256B tsq slot

typedef __attribute__((ext_vector_type(8))) short short8;   // 8 bf16 = 4 VGPR
typedef __attribute__((ext_vector_type(4))) float f32x4;

// fp32 -> bf16 bits, round-to-nearest-even
static __device__ __forceinline__ unsigned short f2bf(float x) {
    unsigned u = __float_as_uint(x);
    unsigned r = u + 0x7FFFu + ((u >> 16) & 1u);
    return (unsigned short)(r >> 16);
}

// v_med3_u32: single-op per-level sorted insert primitive
static __device__ __forceinline__ unsigned med3u(unsigned a, unsigned b, unsigned c) {
    unsigned d;
    asm("v_med3_u32 %0, %1, %2, %3" : "=v"(d) : "v"(a), "v"(b), "v"(c));
    return d;
}

// exact sorted-ascending top-5 insert: 4 med3 + 1 min
static __device__ __forceinline__ void ins5(unsigned st[5], unsigned k) {
    st[4] = med3u(st[4], st[3], k);
    st[3] = med3u(st[3], st[2], k);
    st[2] = med3u(st[2], st[1], k);
    st[1] = med3u(st[1], st[0], k);
    st[0] = st[0] < k ? st[0] : k;
}

// exact sorted-ascending top-10 insert: 9 med3 + 1 min
static __device__ __forceinline__ void ins10(unsigned st[REFK], unsigned k) {
    #pragma unroll
    for (int s = REFK - 1; s >= 1; --s) st[s] = med3u(st[s], st[s - 1], k);
    st[0] = st[0] < k ? st[0] : k;
}

static __device__ __forceinline__ void gload_lds16(const void* g, void* l) {
    __builtin_amdgcn_global_load_lds(
        (const __attribute__((address_space(1))) unsigned*)g,
        (__attribute__((address_space(3))) unsigned*)l, 16, 0, 0);
}
static __device__ __forceinline__ void gload_lds4(const void* g, void* l) {
    __builtin_amdgcn_global_load_lds(
        (const __attribute__((address_space(1))) unsigned*)g,
        (__attribute__((address_space(3))) unsigned*)l, 4, 0, 0);
}

// Phase 0: tgt (fp32) -> tbf = bf16(-2*tgt), PRE-SWIZZLED within each 16-row tile
// (16B-unit u of row r stored at u ^ (r&15)); pad rows (M..Mpad) zeros.
// tsqb = |t|^2 + BIAS (INF pads) for the hot loop; tsqe = exact |t|^2 for refine.
__global__ void prep_kernel(const float* __restrict__ tgt, unsigned short* __restrict__ tbf,
                            float* __restrict__ tsqb, float* __restrict__ tsqe,
                            int M, int Mpad) {
    int row  = blockIdx.x;
    int lane = threadIdx.x;  // 64; handles elems 2*lane, 2*lane+1
    if (row >= Mpad) return;
    float2 v = make_float2(0.f, 0.f);
    if (row < M) v = *(const float2*)(tgt + (size_t)row * D + lane * 2);
    unsigned pack = (unsigned)f2bf(-2.f * v.x) | ((unsigned)f2bf(-2.f * v.y) << 16);
    size_t byte = (size_t)row * 256 + (size_t)(((lane >> 2) ^ (row & 15)) * 16 + (lane & 3) * 4);
    *(unsigned*)((char*)tbf + byte) = pack;
    float ss = v.x * v.x + v.y * v.y;
    #pragma unroll
    for (int off = 1; off < 64; off <<= 1) ss += __shfl_xor(ss, off);
    if (lane == 0) {
        tsqe[row] = ss;
        tsqb[row] = (row < M) ? (ss + BIAS) : __builtin_inff();
    }
}

// Scan: 32-row tiles, TRIPLE-buffered, counted-vmcnt protocol (no vmcnt(0) in loop):
//   per macro t:  STAGE(t+2 -> buf[(t+2)%3]);  COMPUTE(buf[t%3]);
//                 s_waitcnt vmcnt(3); s_barrier     // retires stage(t+1), keeps stage(t+2)
// __launch_bounds__(256,4): VGPR budget 128 (r11's (256,6) squeezed to ~40 -> scratch
// spills -> 1 GB FETCH; this is the single variable changed vs r11).
__global__ __launch_bounds__(256, 4)
void knn_scan(const float* __restrict__ src, const unsigned short* __restrict__ tbf,
              const float* __restrict__ tsqb, unsigned* __restrict__ keys,
              int N, int M, int h0, int msteps) {
    const int tid  = (int)threadIdx.x;
    const int wid  = tid >> 6;
    const int lane = tid & 63;
    const int c16  = lane & 15;   // MFMA col (source slot) / A-row within tile
    const int g    = lane >> 4;   // row-class (C rows 4g..4g+3)
    const int half = blockIdx.y;
    const int colbase = blockIdx.x * (WAVES * SRCS_PER_WAVE) + wid * SRCS_PER_WAVE;

    __shared__ __align__(16) char smem[3 * BUFB];   // 25344 B

    // ---- build source (B) fragments: bf16, k = kk*32 + g*8 + e (matches A packing)
    short8 bfrag[CT][4];
    #pragma unroll
    for (int ct = 0; ct < CT; ++ct) {
        int srow = colbase + ct * 16 + c16;
        if (srow >= N) srow = N - 1;
        const float* sp = src + (size_t)srow * D + g * 8;
        #pragma unroll
        for (int kk = 0; kk < 4; ++kk) {
            float4 v0 = *(const float4*)(sp + kk * 32);
            float4 v1 = *(const float4*)(sp + kk * 32 + 4);
            short8 b;
            b[0] = (short)f2bf(v0.x); b[1] = (short)f2bf(v0.y);
            b[2] = (short)f2bf(v0.z); b[3] = (short)f2bf(v0.w);
            b[4] = (short)f2bf(v1.x); b[5] = (short)f2bf(v1.y);
            b[6] = (short)f2bf(v1.z); b[7] = (short)f2bf(v1.w);
            bfrag[ct][kk] = b;
        }
    }

    unsigned st[CT][5];
    #pragma unroll
    for (int ct = 0; ct < CT; ++ct)
        #pragma unroll
        for (int s = 0; s < 5; ++s) st[ct][s] = 0xFFFFFFFFu;

    // swizzled LDS element offsets (constant per thread)
    int oe[4];
    #pragma unroll
    for (int kk = 0; kk < 4; ++kk) oe[kk] = c16 * 16 + ((g + 4 * kk) ^ c16);

    const int t0 = half ? h0 : 0;
    const int tc = half ? (msteps - h0) : h0;   // 32-row macros in this half (%3==0)
    const int tlast = t0 + tc - 1;

    #define STAGE(tile, b)                                                          \
        do {                                                                        \
            const char* gb_ = (const char*)tbf + (size_t)(tile) * TILEB;            \
            char* lb_ = smem + (size_t)(b) * BUFB;                                  \
            gload_lds16(gb_ + wid * 2048 + lane * 16, lb_ + wid * 2048);            \
            gload_lds16(gb_ + wid * 2048 + 1024 + lane * 16, lb_ + wid * 2048 + 1024);\
            gload_lds4((const char*)tsqb + (size_t)(tile) * 128 + lane * 4,         \
                       lb_ + TILEB);                                                \
        } while (0)

    #define COMPUTE(b)                                                              \
        do {                                                                        \
            const short8* A_ = (const short8*)(smem + (size_t)(b) * BUFB);          \
            const float*  Q_ = (const float*)(smem + (size_t)(b) * BUFB + TILEB);   \
            _Pragma("unroll")                                                       \
            for (int sub_ = 0; sub_ < 2; ++sub_) {                                  \
                short8 a_[4];                                                       \
                _Pragma("unroll")                                                   \
                for (int kk = 0; kk < 4; ++kk) a_[kk] = A_[sub_ * 256 + oe[kk]];    \
                float4 q_ = *(const float4*)(Q_ + sub_ * 16 + g * 4);               \
                _Pragma("unroll")                                                   \
                for (int ct = 0; ct < CT; ++ct) {                                   \
                    f32x4 acc = { q_.x, q_.y, q_.z, q_.w };                         \
                    _Pragma("unroll")                                               \
                    for (int kk = 0; kk < 4; ++kk)                                  \
                        acc = __builtin_amdgcn_mfma_f32_16x16x32_bf16(              \
                                  a_[kk], bfrag[ct][kk], acc, 0, 0, 0);             \
                    _Pragma("unroll")                                               \
                    for (int e = 0; e < 4; ++e) {                                   \
                        unsigned key = (__float_as_uint(acc[e]) & 0xFFFFE000u)      \
                                       | (jb + (unsigned)e);                        \
                        ins5(st[ct], key);                                          \
                    }                                                               \
                }                                                                   \
                jb += 16;                                                           \
            }                                                                       \
        } while (0)

    unsigned jb = (unsigned)(t0 * 32 + g * 4);

    STAGE(t0, 0);
    STAGE(t0 + 1, 1);
    asm volatile("s_waitcnt vmcnt(3)\n\ts_barrier" ::: "memory");   // tile t0 ready

    for (int i = 0; i < tc; i += 3) {
        int t_ = t0 + i;
        int s2 = t_ + 2 < tlast ? t_ + 2 : tlast;
        int s3 = t_ + 3 < tlast ? t_ + 3 : tlast;
        int s4 = t_ + 4 < tlast ? t_ + 4 : tlast;
        STAGE(s2, 2);
        COMPUTE(0);
        asm volatile("s_waitcnt vmcnt(3)\n\ts_barrier" ::: "memory");
        STAGE(s3, 0);
        COMPUTE(1);
        asm volatile("s_waitcnt vmcnt(3)\n\ts_barrier" ::: "memory");
        STAGE(s4, 1);
        COMPUTE(2);
        asm volatile("s_waitcnt vmcnt(3)\n\ts_barrier" ::: "memory");
    }
    asm volatile("s_waitcnt vmcnt(0)" ::: "memory");   // drain dangling clamped stages
    #undef STAGE
    #undef COMPUTE

    // ---- emit candidate keys ----
    #pragma unroll
    for (int ct = 0; ct < CT; ++ct) {
        int srow = colbase + ct * 16 + c16;
        if (srow < N) {
            #pragma unroll
            for (int s = 0; s < 5; ++s)
                keys[(size_t)srow * 40 + half * 20 + g * 5 + s] = st[ct][s];
        }
    }
}

// Merge: 1 thread per source. Top-10 (by truncated bf16 key) of the 40
// candidates, exact fp32 refine of those 10, top-3 + softmax + output.
__global__ __launch_bounds__(256, 4)
void knn_merge(const float* __restrict__ src, const float* __restrict__ tgt,
               const float* __restrict__ tsqe, const unsigned* __restrict__ keys,
               const float* __restrict__ tpts, float* __restrict__ out,
               int N, int M) {
    int i = blockIdx.x * 256 + (int)threadIdx.x;
    if (i >= N) return;

    unsigned best[REFK];
    #pragma unroll
    for (int s = 0; s < REFK; ++s) best[s] = 0xFFFFFFFFu;

    const uint4* kp = (const uint4*)(keys + (size_t)i * 40);
    #pragma unroll
    for (int q = 0; q < 10; ++q) {
        uint4 kv = kp[q];
        ins10(best, kv.x); ins10(best, kv.y); ins10(best, kv.z); ins10(best, kv.w);
    }

    int js[REFK]; float dt[REFK];
    #pragma unroll
    for (int s = 0; s < REFK; ++s) {
        int j = (int)(best[s] & 0x1FFFu);
        js[s] = (j < M) ? j : (M - 1);
        dt[s] = 0.f;
    }

    const float4* sp = (const float4*)(src + (size_t)i * D);
    for (int kc = 0; kc < D / 4; ++kc) {
        float4 sv = sp[kc];
        #pragma unroll
        for (int s = 0; s < REFK; ++s) {
            float4 tv = *(const float4*)(tgt + (size_t)js[s] * D + kc * 4);
            dt[s] = fmaf(sv.x, tv.x, fmaf(sv.y, tv.y, fmaf(sv.z, tv.z, fmaf(sv.w, tv.w, dt[s]))));
        }
    }

    float d0 = __builtin_inff(), d1 = d0, d2 = d0;
    int i0 = 0, i1 = 0, i2 = 0;
    #pragma unroll
    for (int s = 0; s < REFK; ++s) {
        float dd = fmaf(-2.f, dt[s], tsqe[js[s]]);
        int jj = js[s];
        if (dd < d2) {
            if (dd < d1) {
                d2 = d1; i2 = i1;
                if (dd < d0) { d1 = d0; i1 = i0; d0 = dd; i0 = jj; }
                else         { d1 = dd; i1 = jj; }
            } else { d2 = dd; i2 = jj; }
        }
    }

    float e1 = __expf(d0 - d1);
    float e2 = __expf(d0 - d2);
    float inv = 1.f / (1.f + e1 + e2);
    float w0 = inv, w1 = e1 * inv, w2 = e2 * inv;
    const float* p0 = tpts + 3 * (size_t)i0;
    const float* p1 = tpts + 3 * (size_t)i1;
    const float* p2 = tpts + 3 * (size_t)i2;
    out[3 * (size_t)i + 0] = w0 * p0[0] + w1 * p1[0] + w2 * p2[0];
    out[3 * (size_t)i + 1] = w0 * p0[1] + w1 * p1[1] + w2 * p2[1];
    out[3 * (size_t)i + 2] = w0 * p0[2] + w1 * p1[2] + w2 * p2[2];
}

extern "C" void kernel_launch(void* const* d_in, const int* in_sizes, int n_in,
                              void* d_out, int out_size, void* d_ws, size_t ws_size,
                              hipStream_t stream) {
    const float* src  = (const float*)d_in[0];  // [N,128]
    const float* tgt  = (const float*)d_in[1];  // [M,128]
    const float* tpts = (const float*)d_in[2];  // [M,3]
    float* out = (float*)d_out;

    int N = in_sizes[0] / D;
    int M = in_sizes[1] / D;
    int Mpad = (M + 191) & ~191;                // 192-multiple: 6912; msteps %6 == 0
    int msteps = Mpad >> 5;                     // 216 (32-row tiles)
    int h0 = msteps >> 1;                       // 108 (divisible by 3)

    // ws layout: tbf (Mpad*256 B, swizzled) | tsqb (Mpad*4) | tsqe (Mpad*4) |
    //            keys (N*40*4 = 16 MB). Total ~17.8 MB.
    char* w = (char*)d_ws;
    unsigned short* tbf = (unsigned short*)w;                 w += (size_t)Mpad * 256;
    float* tsqb = (float*)w;                                  w += (size_t)Mpad * 4;
    float* tsqe = (float*)w;                                  w += (size_t)Mpad * 4;
    unsigned* keys = (unsigned*)w;

    prep_kernel<<<Mpad, 64, 0, stream>>>(tgt, tbf, tsqb, tsqe, M, Mpad);

    int per_block = WAVES * SRCS_PER_WAVE;                    // 128
    dim3 sgrid((N + per_block - 1) / per_block, 2);           // 782 x 2 = 1564 blocks
    knn_scan<<<sgrid, 256, 0, stream>>>(src, tbf, tsqb, keys, N, M, h0, msteps);

    knn_merge<<<(N + 255) / 256, 256, 0, stream>>>(src, tgt, tsqe, keys, tpts, out, N, M);
}

// Round 14
// 402.066 us; speedup vs baseline: 1.7766x; 1.0374x over previous
//
#include <hip/hip_runtime.h>
#include <math.h>

#define D 128
#define WAVES 4                    // waves per block; block covers 128 sources
#define BIAS 16.0f
#define TILEB 8192                 // 32-row A-tile bytes
#define BUFB  8448                 // tile + 256B tshl slot
#define REFK 10

typedef __attribute__((ext_vector_type(8))) short short8;    // 8 bf16
typedef __attribute__((ext_vector_type(16))) float f32x16;   // 32x32 acc

union U8 { short8 s; unsigned u[4]; };

// fp32 -> bf16 bits, round-to-nearest-even
static __device__ __forceinline__ unsigned short f2bf(float x) {
    unsigned u = __float_as_uint(x);
    unsigned r = u + 0x7FFFu + ((u >> 16) & 1u);
    return (unsigned short)(r >> 16);
}

static __device__ __forceinline__ unsigned med3u(unsigned a, unsigned b, unsigned c) {
    unsigned d;
    asm("v_med3_u32 %0, %1, %2, %3" : "=v"(d) : "v"(a), "v"(b), "v"(c));
    return d;
}

// exact sorted-ascending top-5 insert: 4 med3 + 1 min (validated r6-r12)
static __device__ __forceinline__ void ins5(unsigned st[5], unsigned k) {
    st[4] = med3u(st[4], st[3], k);
    st[3] = med3u(st[3], st[2], k);
    st[2] = med3u(st[2], st[1], k);
    st[1] = med3u(st[1], st[0], k);
    st[0] = st[0] < k ? st[0] : k;
}

// exact sorted-ascending top-10 insert: 9 med3 + 1 min (validated r9-r12)
static __device__ __forceinline__ void ins10(unsigned st[REFK], unsigned k) {
    #pragma unroll
    for (int s = REFK - 1; s >= 1; --s) st[s] = med3u(st[s], st[s - 1], k);
    st[0] = st[0] < k ? st[0] : k;
}

static __device__ __forceinline__ void gload_lds16(const void* g, void* l) {
    __builtin_amdgcn_global_load_lds(
        (const __attribute__((address_space(1))) unsigned*)g,
        (__attribute__((address_space(3))) unsigned*)l, 16, 0, 0);
}
static __device__ __forceinline__ void gload_lds4(const void* g, void* l) {
    __builtin_amdgcn_global_load_lds(
        (const __attribute__((address_space(1))) unsigned*)g,
        (__attribute__((address_space(3))) unsigned*)l, 4, 0, 0);
}

// Phase 0: tbf = bf16(-2*tgt), PRE-SWIZZLED (16B-unit u of row r at u^(r&15));
// pad rows zero. tshl[t][0..31] = (hi,lo) bf16 split of tsq+BIAS (large-finite
// for pads), tshl[t][32..63] = 0 (zero source for hi=1 lanes). tsqe = exact |t|^2.
__global__ void prep_kernel(const float* __restrict__ tgt, unsigned short* __restrict__ tbf,
                            unsigned* __restrict__ tshl, float* __restrict__ tsqe,
                            int M, int Mpad) {
    int row  = blockIdx.x;
    int lane = threadIdx.x;  // 64
    if (row >= Mpad) return;
    float2 v = make_float2(0.f, 0.f);
    if (row < M) v = *(const float2*)(tgt + (size_t)row * D + lane * 2);
    unsigned pack = (unsigned)f2bf(-2.f * v.x) | ((unsigned)f2bf(-2.f * v.y) << 16);
    size_t byte = (size_t)row * 256 + (size_t)(((lane >> 2) ^ (row & 15)) * 16 + (lane & 3) * 4);
    *(unsigned*)((char*)tbf + byte) = pack;
    float ss = v.x * v.x + v.y * v.y;
    #pragma unroll
    for (int off = 1; off < 64; off <<= 1) ss += __shfl_xor(ss, off);
    if (lane == 0) {
        tsqe[row] = ss;
        float pv = (row < M) ? (ss + BIAS) : 1e30f;
        unsigned hv = f2bf(pv);
        float hf = __uint_as_float(hv << 16);
        unsigned lv = f2bf(pv - hf);
        int t = row >> 5, r = row & 31;
        tshl[t * 64 + r]      = hv | (lv << 16);
        tshl[t * 64 + 32 + r] = 0;
    }
}

// Scan: 32x32x16-bf16 MFMA core (9 MFMA per 1024 distances: 1 tsq-fold + 8 K-slices).
// Per thread TWO depth-5 chains (C-regs 0-7 / 8-15) -> per source 8 chains x top-5
// = 40 keys (same candidate statistics as validated r9/r12). Triple-buffered
// counted-vmcnt protocol (r12-validated). key = distbits[31:13] | tile<<5|hi<<4|reg.
__global__ __launch_bounds__(256, 4)
void knn_scan(const float* __restrict__ src, const unsigned short* __restrict__ tbf,
              const unsigned* __restrict__ tshl, unsigned* __restrict__ keys,
              int N, int M, int h0, int msteps) {
    const int tid  = (int)threadIdx.x;
    const int wid  = tid >> 6;
    const int lane = tid & 63;
    const int col  = lane & 31;   // B col (source) and A row (target)
    const int hi   = lane >> 5;   // k-half
    const int half = blockIdx.y;
    const int colbase = blockIdx.x * (WAVES * 32) + wid * 32;
    const int srow = colbase + col;
    const int srcl = srow < N ? srow : (N - 1);

    __shared__ __align__(16) char smem[3 * BUFB];   // 25344 B

    // ---- B fragments: source srcl, k = 16m + 8*hi + e
    short8 bfrag[8];
    {
        const float* sp = src + (size_t)srcl * D + hi * 8;
        #pragma unroll
        for (int m = 0; m < 8; ++m) {
            float4 v0 = *(const float4*)(sp + m * 16);
            float4 v1 = *(const float4*)(sp + m * 16 + 4);
            short8 b;
            b[0] = (short)f2bf(v0.x); b[1] = (short)f2bf(v0.y);
            b[2] = (short)f2bf(v0.z); b[3] = (short)f2bf(v0.w);
            b[4] = (short)f2bf(v1.x); b[5] = (short)f2bf(v1.y);
            b[6] = (short)f2bf(v1.z); b[7] = (short)f2bf(v1.w);
            bfrag[m] = b;
        }
    }

    // b2: ones at slots (hi=0, e=0,1) pairing with tshl hi/lo; zero for hi=1
    U8 b2u; b2u.u[0] = hi ? 0u : 0x3F803F80u; b2u.u[1] = 0; b2u.u[2] = 0; b2u.u[3] = 0;

    f32x16 zz;
    #pragma unroll
    for (int e = 0; e < 16; ++e) zz[e] = 0.f;

    // A-read byte offsets (swizzled): elems k=16m+8hi of row `col`
    int aoff[8];
    #pragma unroll
    for (int m = 0; m < 8; ++m) aoff[m] = col * 256 + (((2 * m + hi) ^ (col & 15)) * 16);
    const int toff = TILEB + col * 4 + hi * 128;   // hi=1 lanes read zeros

    unsigned stA[5], stB[5];
    #pragma unroll
    for (int s = 0; s < 5; ++s) { stA[s] = 0xFFFFFFFFu; stB[s] = 0xFFFFFFFFu; }
    const unsigned hib = (unsigned)(hi << 4);

    const int t0 = half ? h0 : 0;
    const int tc = half ? (msteps - h0) : h0;   // %3 == 0 by padding
    const int tlast = t0 + tc - 1;

    #define STAGE(tile, b)                                                          \
        do {                                                                        \
            const char* gb_ = (const char*)tbf + (size_t)(tile) * TILEB;            \
            char* lb_ = smem + (size_t)(b) * BUFB;                                  \
            gload_lds16(gb_ + wid * 2048 + lane * 16, lb_ + wid * 2048);            \
            gload_lds16(gb_ + wid * 2048 + 1024 + lane * 16, lb_ + wid * 2048 + 1024);\
            gload_lds4((const char*)tshl + (size_t)(tile) * 256 + lane * 4,         \
                       lb_ + TILEB);                                                \
        } while (0)

    #define COMPUTE(b, tile)                                                        \
        do {                                                                        \
            const char* base_ = smem + (size_t)(b) * BUFB;                          \
            unsigned pair_ = *(const unsigned*)(base_ + toff);                      \
            U8 a2u_; a2u_.u[0] = pair_; a2u_.u[1] = 0; a2u_.u[2] = 0; a2u_.u[3] = 0;\
            f32x16 acc = __builtin_amdgcn_mfma_f32_32x32x16_bf16(a2u_.s, b2u.s, zz, 0, 0, 0);\
            _Pragma("unroll")                                                       \
            for (int m = 0; m < 8; ++m) {                                           \
                short8 am_ = *(const short8*)(base_ + aoff[m]);                     \
                acc = __builtin_amdgcn_mfma_f32_32x32x16_bf16(am_, bfrag[m], acc, 0, 0, 0);\
            }                                                                       \
            unsigned vb_ = ((unsigned)(tile) << 5) | hib;                           \
            _Pragma("unroll")                                                       \
            for (int r = 0; r < 8; ++r) {                                           \
                unsigned key_ = (__float_as_uint(acc[r]) & 0xFFFFE000u) | vb_ | (unsigned)r;\
                ins5(stA, key_);                                                    \
            }                                                                       \
            _Pragma("unroll")                                                       \
            for (int r = 8; r < 16; ++r) {                                          \
                unsigned key_ = (__float_as_uint(acc[r]) & 0xFFFFE000u) | vb_ | (unsigned)r;\
                ins5(stB, key_);                                                    \
            }                                                                       \
        } while (0)

    STAGE(t0, 0);
    STAGE(t0 + 1, 1);
    asm volatile("s_waitcnt vmcnt(3)\n\ts_barrier" ::: "memory");   // tile t0 ready

    for (int i = 0; i < tc; i += 3) {
        int t_ = t0 + i;
        int s2 = t_ + 2 < tlast ? t_ + 2 : tlast;
        int s3 = t_ + 3 < tlast ? t_ + 3 : tlast;
        int s4 = t_ + 4 < tlast ? t_ + 4 : tlast;
        STAGE(s2, 2);
        COMPUTE(0, t_);
        asm volatile("s_waitcnt vmcnt(3)\n\ts_barrier" ::: "memory");
        STAGE(s3, 0);
        COMPUTE(1, t_ + 1);
        asm volatile("s_waitcnt vmcnt(3)\n\ts_barrier" ::: "memory");
        STAGE(s4, 1);
        COMPUTE(2, t_ + 2);
        asm volatile("s_waitcnt vmcnt(3)\n\ts_barrier" ::: "memory");
    }
    asm volatile("s_waitcnt vmcnt(0)" ::: "memory");
    #undef STAGE
    #undef COMPUTE

    if (srow < N) {
        unsigned* kp = keys + (size_t)srow * 40 + half * 20 + hi * 10;
        #pragma unroll
        for (int s = 0; s < 5; ++s) { kp[s] = stA[s]; kp[5 + s] = stB[s]; }
    }
}

// Merge: 1 thread per source. Top-10 (by truncated bf16 key) of the 40
// candidates, decode, exact fp32 refine of those 10, top-3 + softmax + output.
__global__ __launch_bounds__(256, 4)
void knn_merge(const float* __restrict__ src, const float* __restrict__ tgt,
               const float* __restrict__ tsqe, const unsigned* __restrict__ keys,
               const float* __restrict__ tpts, float* __restrict__ out,
               int N, int M) {
    int i = blockIdx.x * 256 + (int)threadIdx.x;
    if (i >= N) return;

    unsigned best[REFK];
    #pragma unroll
    for (int s = 0; s < REFK; ++s) best[s] = 0xFFFFFFFFu;

    const uint4* kp = (const uint4*)(keys + (size_t)i * 40);
    #pragma unroll
    for (int q = 0; q < 10; ++q) {
        uint4 kv = kp[q];
        ins10(best, kv.x); ins10(best, kv.y); ins10(best, kv.z); ins10(best, kv.w);
    }

    int js[REFK]; float dt[REFK];
    #pragma unroll
    for (int s = 0; s < REFK; ++s) {
        unsigned idx = best[s] & 0x1FFFu;
        int tile = (int)(idx >> 5);
        int hh   = (int)((idx >> 4) & 1u);
        int reg  = (int)(idx & 15u);
        int row  = tile * 32 + (reg & 3) + 8 * (reg >> 2) + 4 * hh;
        js[s] = (row < M) ? row : (M - 1);
        dt[s] = 0.f;
    }

    const float4* sp = (const float4*)(src + (size_t)i * D);
    for (int kc = 0; kc < D / 4; ++kc) {
        float4 sv = sp[kc];
        #pragma unroll
        for (int s = 0; s < REFK; ++s) {
            float4 tv = *(const float4*)(tgt + (size_t)js[s] * D + kc * 4);
            dt[s] = fmaf(sv.x, tv.x, fmaf(sv.y, tv.y, fmaf(sv.z, tv.z, fmaf(sv.w, tv.w, dt[s]))));
        }
    }

    float d0 = __builtin_inff(), d1 = d0, d2 = d0;
    int i0 = 0, i1 = 0, i2 = 0;
    #pragma unroll
    for (int s = 0; s < REFK; ++s) {
        float dd = fmaf(-2.f, dt[s], tsqe[js[s]]);
        int jj = js[s];
        if (dd < d2) {
            if (dd < d1) {
                d2 = d1; i2 = i1;
                if (dd < d0) { d1 = d0; i1 = i0; d0 = dd; i0 = jj; }
                else         { d1 = dd; i1 = jj; }
            } else { d2 = dd; i2 = jj; }
        }
    }

    float e1 = __expf(d0 - d1);
    float e2 = __expf(d0 - d2);
    float inv = 1.f / (1.f + e1 + e2);
    float w0 = inv, w1 = e1 * inv, w2 = e2 * inv;
    const float* p0 = tpts + 3 * (size_t)i0;
    const float* p1 = tpts + 3 * (size_t)i1;
    const float* p2 = tpts + 3 * (size_t)i2;
    out[3 * (size_t)i + 0] = w0 * p0[0] + w1 * p1[0] + w2 * p2[0];
    out[3 * (size_t)i + 1] = w0 * p0[1] + w1 * p1[1] + w2 * p2[1];
    out[3 * (size_t)i + 2] = w0 * p0[2] + w1 * p1[2] + w2 * p2[2];
}

extern "C" void kernel_launch(void* const* d_in, const int* in_sizes, int n_in,
                              void* d_out, int out_size, void* d_ws, size_t ws_size,
                              hipStream_t stream) {
    const float* src  = (const float*)d_in[0];  // [N,128]
    const float* tgt  = (const float*)d_in[1];  // [M,128]
    const float* tpts = (const float*)d_in[2];  // [M,3]
    float* out = (float*)d_out;

    int N = in_sizes[0] / D;
    int M = in_sizes[1] / D;
    int Mpad = (M + 191) & ~191;                // 6912; msteps % 6 == 0
    int msteps = Mpad >> 5;                     // 216
    int h0 = msteps >> 1;                       // 108 (div by 3)

    // ws: tbf (Mpad*256, swizzled) | tshl (msteps*256) | tsqe (Mpad*4) | keys (N*40*4)
    char* w = (char*)d_ws;
    unsigned short* tbf = (unsigned short*)w;                 w += (size_t)Mpad * 256;
    unsigned* tshl = (unsigned*)w;                            w += (size_t)msteps * 256;
    float* tsqe = (float*)w;                                  w += (size_t)Mpad * 4;
    unsigned* keys = (unsigned*)w;

    prep_kernel<<<Mpad, 64, 0, stream>>>(tgt, tbf, tshl, tsqe, M, Mpad);

    dim3 sgrid((N + 127) / 128, 2);             // 782 x 2
    knn_scan<<<sgrid, 256, 0, stream>>>(src, tbf, tshl, keys, N, M, h0, msteps);

    knn_merge<<<(N + 255) / 256, 256, 0, stream>>>(src, tgt, tsqe, keys, tpts, out, N, M);
}